// Round 1
// baseline (1721.587 us; speedup 1.0000x reference)
//
#include <hip/hip_runtime.h>

#define BB   8
#define CIN  16
#define COUT 32
#define DD   64
#define NUM_W (CIN * COUT * 27)   // 13824
#define NUM_P (NUM_W + COUT)      // 13856

// ws layout (floats): [0,64) h1 (8x8); [64, 64+8*NUM_P) params. ~443 KB total.

__global__ void hyper_h1_kernel(const float* __restrict__ features,
                                const float* __restrict__ fc0_w,
                                const float* __restrict__ fc0_b,
                                const float* __restrict__ a0,
                                const float* __restrict__ fc1_w,
                                const float* __restrict__ fc1_b,
                                const float* __restrict__ a1,
                                float* __restrict__ h1out) {
    __shared__ float h0[8][16];
    const int t = threadIdx.x;  // 128 threads
    if (t < 128) {
        const int b = t >> 4, i = t & 15;
        float s = fc0_b[i];
        #pragma unroll
        for (int j = 0; j < 10; ++j) s += features[b * 10 + j] * fc0_w[i * 10 + j];
        const float a = a0[0];
        h0[b][i] = (s >= 0.f) ? s : a * s;
    }
    __syncthreads();
    if (t < 64) {
        const int b = t >> 3, i = t & 7;
        float s = fc1_b[i];
        #pragma unroll
        for (int j = 0; j < 16; ++j) s += h0[b][j] * fc1_w[i * 16 + j];
        const float a = a1[0];
        h1out[b * 8 + i] = (s >= 0.f) ? s : a * s;
    }
}

__global__ void hyper_params_kernel(const float* __restrict__ h1,
                                    const float* __restrict__ wg_w,
                                    const float* __restrict__ wg_b,
                                    float* __restrict__ params) {
    const int b = blockIdx.y;
    const int p = blockIdx.x * 256 + threadIdx.x;
    if (p >= NUM_P) return;
    float s = wg_b[p];
    #pragma unroll
    for (int j = 0; j < 8; ++j) s += h1[b * 8 + j] * wg_w[p * 8 + j];
    params[b * NUM_P + p] = s;
}

// Direct conv. Block = 256 threads: 16 w-groups (4 outputs each) x 16 h-rows,
// at one d-slice, one b, one co-quad (4 consecutive co).
// grid: x = 4 (h tiles of 16), y = 64 (d), z = 64 (b*8 + co_quad)
__global__ __launch_bounds__(256) void conv_kernel(
        const float* __restrict__ x,
        const float* __restrict__ params,
        float* __restrict__ out) {
    const int t     = threadIdx.x;
    const int wq    = t & 15;          // w group
    const int hr    = t >> 4;          // 0..15
    const int h     = blockIdx.x * 16 + hr;
    const int d     = blockIdx.y;
    const int z     = blockIdx.z;
    const int coq   = z & 7;
    const int b     = z >> 3;
    const int w0    = wq * 4;
    const int co0   = coq * 4;

    const float* __restrict__ wbase = params + b * NUM_P + co0 * (CIN * 27);

    float acc[4][4];
    #pragma unroll
    for (int c = 0; c < 4; ++c)
        #pragma unroll
        for (int j = 0; j < 4; ++j) acc[c][j] = 0.f;

    for (int ci = 0; ci < CIN; ++ci) {
        const float* __restrict__ xci = x + ((size_t)(b * CIN + ci)) * (DD * DD * DD);
        #pragma unroll
        for (int kd = 0; kd < 3; ++kd) {
            const int zd = d + kd - 1;
            if (zd < 0 || zd >= DD) continue;
            #pragma unroll
            for (int kh = 0; kh < 3; ++kh) {
                const int zh = h + kh - 1;
                if (zh < 0 || zh >= DD) continue;
                const float* __restrict__ xrow = xci + (zd * DD + zh) * DD;
                // xv[j] = xrow[w0 - 1 + j], j = 0..5, zero outside [0,64)
                const float4 mid = *(const float4*)(xrow + w0);   // 16B aligned
                float xv[6];
                xv[0] = (w0 > 0)        ? xrow[w0 - 1] : 0.f;
                xv[1] = mid.x; xv[2] = mid.y; xv[3] = mid.z; xv[4] = mid.w;
                xv[5] = (w0 < DD - 4)   ? xrow[w0 + 4] : 0.f;
                // block-uniform weight reads (expect s_load)
                const int wk = ci * 27 + (kd * 3 + kh) * 3;
                #pragma unroll
                for (int c = 0; c < 4; ++c) {
                    const float wgt0 = wbase[c * (CIN * 27) + wk + 0];
                    const float wgt1 = wbase[c * (CIN * 27) + wk + 1];
                    const float wgt2 = wbase[c * (CIN * 27) + wk + 2];
                    #pragma unroll
                    for (int j = 0; j < 4; ++j) {
                        acc[c][j] += wgt0 * xv[j + 0];
                        acc[c][j] += wgt1 * xv[j + 1];
                        acc[c][j] += wgt2 * xv[j + 2];
                    }
                }
            }
        }
    }

    const float* __restrict__ bias = params + b * NUM_P + NUM_W;
    #pragma unroll
    for (int c = 0; c < 4; ++c) {
        const float bv = bias[co0 + c];
        float4 o;
        o.x = acc[c][0] + bv;
        o.y = acc[c][1] + bv;
        o.z = acc[c][2] + bv;
        o.w = acc[c][3] + bv;
        float* orow = out + (((size_t)(b * COUT + co0 + c) * DD + d) * DD + h) * DD + w0;
        *(float4*)orow = o;
    }
}

extern "C" void kernel_launch(void* const* d_in, const int* in_sizes, int n_in,
                              void* d_out, int out_size, void* d_ws, size_t ws_size,
                              hipStream_t stream) {
    const float* x        = (const float*)d_in[0];
    const float* features = (const float*)d_in[1];
    const float* fc0_w    = (const float*)d_in[2];
    const float* fc0_b    = (const float*)d_in[3];
    const float* a0       = (const float*)d_in[4];
    const float* fc1_w    = (const float*)d_in[5];
    const float* fc1_b    = (const float*)d_in[6];
    const float* a1       = (const float*)d_in[7];
    const float* wg_w     = (const float*)d_in[8];
    const float* wg_b     = (const float*)d_in[9];

    float* ws     = (float*)d_ws;
    float* h1     = ws;        // 64 floats
    float* params = ws + 64;   // 8 * NUM_P floats

    hyper_h1_kernel<<<1, 128, 0, stream>>>(features, fc0_w, fc0_b, a0,
                                           fc1_w, fc1_b, a1, h1);
    hyper_params_kernel<<<dim3((NUM_P + 255) / 256, BB), 256, 0, stream>>>(
        h1, wg_w, wg_b, params);
    conv_kernel<<<dim3(4, DD, 64), 256, 0, stream>>>(x, params, (float*)d_out);
}

// Round 2
// 545.702 us; speedup vs baseline: 3.1548x; 3.1548x over previous
//
#include <hip/hip_runtime.h>

typedef short short8 __attribute__((ext_vector_type(8)));
typedef float floatx4 __attribute__((ext_vector_type(4)));

#define BB   8
#define CIN  16
#define COUT 32
#define DD   64
#define NUM_W (CIN * COUT * 27)   // 13824
#define NUM_P (NUM_W + COUT)      // 13856
#define KPAD  448                 // 28 taps * 16 ci (tap 27 = zeros)

// ws layout (floats): [0,64) h1 (8x8); [64,320) bias (8x32);
// [320, ...) A_bf16 as shorts: 8*32*448 shorts = 229376 B. Total ~231 KB.

__device__ __forceinline__ short f2bf(float f) {
    union { float f; unsigned u; } v; v.f = f;
    unsigned r = v.u + 0x7FFF + ((v.u >> 16) & 1);   // RNE
    return (short)(r >> 16);
}

__global__ void hyper_kernel(const float* __restrict__ features,
                             const float* __restrict__ fc0_w,
                             const float* __restrict__ fc0_b,
                             const float* __restrict__ a0,
                             const float* __restrict__ fc1_w,
                             const float* __restrict__ fc1_b,
                             const float* __restrict__ a1,
                             const float* __restrict__ wg_w,
                             const float* __restrict__ wg_b,
                             float* __restrict__ h1out,
                             float* __restrict__ biasout) {
    __shared__ float h0[8][16];
    __shared__ float h1s[8][8];
    const int t = threadIdx.x;  // 256
    if (t < 128) {
        const int b = t >> 4, i = t & 15;
        float s = fc0_b[i];
        #pragma unroll
        for (int j = 0; j < 10; ++j) s += features[b * 10 + j] * fc0_w[i * 10 + j];
        const float a = a0[0];
        h0[b][i] = (s >= 0.f) ? s : a * s;
    }
    __syncthreads();
    if (t < 64) {
        const int b = t >> 3, i = t & 7;
        float s = fc1_b[i];
        #pragma unroll
        for (int j = 0; j < 16; ++j) s += h0[b][j] * fc1_w[i * 16 + j];
        const float a = a1[0];
        const float r = (s >= 0.f) ? s : a * s;
        h1s[b][i] = r;
        h1out[b * 8 + i] = r;
    }
    __syncthreads();
    {   // biases: 256 threads = 8 b x 32 co
        const int b = t >> 5, co = t & 31;
        const int p = NUM_W + co;
        float s = wg_b[p];
        #pragma unroll
        for (int j = 0; j < 8; ++j) s += h1s[b][j] * wg_w[p * 8 + j];
        biasout[b * 32 + co] = s;
    }
}

// A_bf16[b][co][k], k = tap*16 + ci, tap = kd*9+kh*3+kw, zero for tap==27
__global__ void wgen_kernel(const float* __restrict__ h1,
                            const float* __restrict__ wg_w,
                            const float* __restrict__ wg_b,
                            short* __restrict__ A) {
    const int b  = blockIdx.y;
    const int id = blockIdx.x * 256 + threadIdx.x;  // [0, 32*28*16)
    const int ci  = id & 15;
    const int tmp = id >> 4;          // co*28 + tap
    const int tap = tmp % 28;
    const int co  = tmp / 28;
    float val = 0.f;
    if (tap < 27) {
        const int p = co * 432 + ci * 27 + tap;
        float s = wg_b[p];
        #pragma unroll
        for (int j = 0; j < 8; ++j) s += h1[b * 8 + j] * wg_w[p * 8 + j];
        val = s;
    }
    A[(b * 32 + co) * KPAD + tap * 16 + ci] = f2bf(val);
}

// Implicit-GEMM conv via MFMA 16x16x32 bf16.
// Block = 256 thr = 4 waves; tile = (b, d, h0..h0+3, w 0..63).
// LDS x-patch: [dz 3][hz 6][wz 66][ci 16] bf16, ci innermost -> B-frag = 1 ds_read_b128.
__global__ __launch_bounds__(256, 2) void conv_mfma_kernel(
        const float* __restrict__ x,
        const short* __restrict__ A,
        const float* __restrict__ bias,
        float* __restrict__ out) {
    __shared__ uint4 xs4[2376];            // 19008 shorts = 3*6*66*16
    short* xs = (short*)xs4;

    const int t    = threadIdx.x;
    const int lane = t & 63;
    const int wave = t >> 6;
    const int n16  = lane & 15;
    const int q    = lane >> 4;
    const int h0   = blockIdx.x * 4;
    const int d    = blockIdx.y;
    const int b    = blockIdx.z;

    // ---- preload all A-fragments (L2-hot, 13.5 KB per sample) ----
    short8 afrag[14][2];
    const short* Ab = A + (size_t)(b * 32) * KPAD;
    #pragma unroll
    for (int c = 0; c < 14; ++c)
        #pragma unroll
        for (int mt = 0; mt < 2; ++mt) {
            const int co = mt * 16 + n16;          // A: m = lane&15
            afrag[c][mt] = *(const short8*)(Ab + co * KPAD + c * 32 + q * 8);
        }

    // ---- zero LDS (halo/pad) ----
    const uint4 z4 = {0u, 0u, 0u, 0u};
    #pragma unroll
    for (int i = 0; i < 10; ++i) {
        const int idx = t + i * 256;
        if (idx < 2376) xs4[idx] = z4;
    }
    __syncthreads();

    // ---- stage x -> LDS bf16 (coalesced float4 reads) ----
    const int ci_s = wave * 4 + q;        // 0..15
    const int w4   = n16 * 4;
    #pragma unroll
    for (int i = 0; i < 18; ++i) {
        const int dz = i / 6, hz = i % 6;
        const int zd = d + dz - 1;
        const int zh = h0 + hz - 1;
        if (zd >= 0 && zd < DD && zh >= 0 && zh < DD) {
            const float4 v = *(const float4*)(
                x + (((size_t)(b * CIN + ci_s) * DD + zd) * DD + zh) * DD + w4);
            const int base = ((dz * 6 + hz) * 66 + (w4 + 1)) * 16 + ci_s;
            xs[base]      = f2bf(v.x);
            xs[base + 16] = f2bf(v.y);
            xs[base + 32] = f2bf(v.z);
            xs[base + 48] = f2bf(v.w);
        }
    }
    __syncthreads();

    // ---- K-loop: 14 chunks x (4 n-tiles x 2 m-tiles) MFMA ----
    floatx4 acc[2][4];
    #pragma unroll
    for (int mt = 0; mt < 2; ++mt)
        #pragma unroll
        for (int nt = 0; nt < 4; ++nt) acc[mt][nt] = (floatx4){0.f, 0.f, 0.f, 0.f};

    const int ci_base = (q & 1) * 8;
    const int qh      = q >> 1;
    #pragma unroll
    for (int c = 0; c < 14; ++c) {
        int tap = 2 * c + qh;
        if (tap > 26) tap = 26;                 // A is zero for k>=432, B value irrelevant
        const int kd = tap / 9;
        const int r  = tap - kd * 9;
        const int kh = r / 3;
        const int kw = r - kh * 3;
        const int rowbase = ((kd * 6 + wave + kh) * 66 + kw) * 16 + ci_base;
        #pragma unroll
        for (int nt = 0; nt < 4; ++nt) {
            const short8 bfrag = *(const short8*)(xs + rowbase + (nt * 16 + n16) * 16);
            acc[0][nt] = __builtin_amdgcn_mfma_f32_16x16x32_bf16(
                             afrag[c][0], bfrag, acc[0][nt], 0, 0, 0);
            acc[1][nt] = __builtin_amdgcn_mfma_f32_16x16x32_bf16(
                             afrag[c][1], bfrag, acc[1][nt], 0, 0, 0);
        }
    }

    // ---- epilogue: C/D layout col=lane&15(w), row=q*4+reg(co) ----
    const int hh = h0 + wave;
    #pragma unroll
    for (int mt = 0; mt < 2; ++mt) {
        const floatx4 bv = *(const floatx4*)(bias + b * 32 + mt * 16 + q * 4);
        #pragma unroll
        for (int nt = 0; nt < 4; ++nt) {
            const int w = nt * 16 + n16;
            #pragma unroll
            for (int reg = 0; reg < 4; ++reg) {
                const int co = mt * 16 + q * 4 + reg;
                out[(((size_t)(b * COUT + co) * DD + d) * DD + hh) * DD + w] =
                    acc[mt][nt][reg] + bv[reg];
            }
        }
    }
}

extern "C" void kernel_launch(void* const* d_in, const int* in_sizes, int n_in,
                              void* d_out, int out_size, void* d_ws, size_t ws_size,
                              hipStream_t stream) {
    const float* x        = (const float*)d_in[0];
    const float* features = (const float*)d_in[1];
    const float* fc0_w    = (const float*)d_in[2];
    const float* fc0_b    = (const float*)d_in[3];
    const float* a0       = (const float*)d_in[4];
    const float* fc1_w    = (const float*)d_in[5];
    const float* fc1_b    = (const float*)d_in[6];
    const float* a1       = (const float*)d_in[7];
    const float* wg_w     = (const float*)d_in[8];
    const float* wg_b     = (const float*)d_in[9];

    float* ws    = (float*)d_ws;
    float* h1    = ws;                // 64 floats
    float* biasp = ws + 64;           // 256 floats
    short* A     = (short*)(ws + 320);  // 8*32*448 shorts

    hyper_kernel<<<1, 256, 0, stream>>>(features, fc0_w, fc0_b, a0,
                                        fc1_w, fc1_b, a1, wg_w, wg_b, h1, biasp);
    wgen_kernel<<<dim3(56, BB), 256, 0, stream>>>(h1, wg_w, wg_b, A);
    conv_mfma_kernel<<<dim3(16, DD, BB), 256, 0, stream>>>(x, A, biasp, (float*)d_out);
}